// Round 7
// baseline (421.809 us; speedup 1.0000x reference)
//
#include <hip/hip_runtime.h>

#define B_ 32
#define S_ 2048
#define H_ 1024

typedef __attribute__((ext_vector_type(8))) short short8;
typedef __attribute__((ext_vector_type(4))) float f32x4;
typedef __attribute__((ext_vector_type(4))) unsigned short u16x4;

__device__ __forceinline__ unsigned short f2bf(float f) {
    unsigned u = __builtin_bit_cast(unsigned, f);
    u += 0x7FFFu + ((u >> 16) & 1u);
    return (unsigned short)(u >> 16);
}
__device__ __forceinline__ unsigned pk2(float x, float y) {
    return (unsigned)f2bf(x) | ((unsigned)f2bf(y) << 16);
}
__device__ __forceinline__ float bf2f(unsigned short u) {
    unsigned x = ((unsigned)u) << 16;
    return __builtin_bit_cast(float, x);
}
__device__ __forceinline__ void gload16(const void* g, void* l) {
    __builtin_amdgcn_global_load_lds((const __attribute__((address_space(1))) void*)g,
                                     (__attribute__((address_space(3))) void*)l, 16, 0, 0);
}

#define WAITV(nstr) asm volatile("s_waitcnt vmcnt(" nstr ")" ::: "memory")
#define BAR() __builtin_amdgcn_s_barrier()

// ---------- enc fp32 -> bf16 ----------
__global__ void k_cvt(const float* __restrict__ in, uint4* __restrict__ out, int ngroups) {
    int i = blockIdx.x * blockDim.x + threadIdx.x;
    int stride = gridDim.x * blockDim.x;
    for (; i < ngroups; i += stride) {
        const float4* p = (const float4*)in + (size_t)i * 2;
        float4 x = p[0], y = p[1];
        out[i] = make_uint4(pk2(x.x, x.y), pk2(x.z, x.w), pk2(y.x, y.y), pk2(y.z, y.w));
    }
}

// ---------- prep: Wh (K,N) fp32 -> WhT (N,K) bf16 ----------
__global__ void k_whT(const float* __restrict__ Wh, unsigned short* __restrict__ whT) {
    __shared__ float tile[64][65];
    int k0 = blockIdx.x * 64, n0 = blockIdx.y * 64;
    int tx = threadIdx.x, ty = threadIdx.y; // (64,4)
    #pragma unroll
    for (int i = 0; i < 16; ++i) {
        int r = ty + i * 4;
        tile[r][tx] = Wh[(size_t)(k0 + r) * H_ + n0 + tx];
    }
    __syncthreads();
    #pragma unroll
    for (int i = 0; i < 16; ++i) {
        int r = ty + i * 4;
        whT[(size_t)(n0 + r) * H_ + k0 + tx] = f2bf(tile[tx][r]);
    }
}

// ---------- prep: decp[b][n] = ds[b]@Ws[:,n] + bs[n] + bh[n] ----------
__global__ void k_decp(const float* __restrict__ ds, const float* __restrict__ Ws,
                       const float* __restrict__ bs, const float* __restrict__ bh,
                       float* __restrict__ decp) {
    int n = blockIdx.x * 256 + threadIdx.x;
    int b = blockIdx.y;
    float a0 = 0.f, a1 = 0.f, a2 = 0.f, a3 = 0.f;
    for (int h = 0; h < H_; h += 4) {
        a0 += ds[b * H_ + h + 0] * Ws[(size_t)(h + 0) * H_ + n];
        a1 += ds[b * H_ + h + 1] * Ws[(size_t)(h + 1) * H_ + n];
        a2 += ds[b * H_ + h + 2] * Ws[(size_t)(h + 2) * H_ + n];
        a3 += ds[b * H_ + h + 3] * Ws[(size_t)(h + 3) * H_ + n];
    }
    decp[b * H_ + n] = a0 + a1 + a2 + a3 + bs[n] + bh[n];
}

// ---------- prep: covp[b] = cov[b]@Wc + bc ----------
__global__ void k_covp(const float* __restrict__ cov, const float* __restrict__ Wc,
                       const float* __restrict__ bc, float* __restrict__ covp) {
    int b = blockIdx.x, t = threadIdx.x;
    float p = 0.f;
    for (int s = t; s < S_; s += 256) p += cov[b * S_ + s] * Wc[s];
    for (int off = 32; off; off >>= 1) p += __shfl_down(p, off);
    __shared__ float w[4];
    if ((t & 63) == 0) w[t >> 6] = p;
    __syncthreads();
    if (t == 0) covp[b] = w[0] + w[1] + w[2] + w[3] + bc[0];
}

// ---------- shared epilogue: tanh + V-dot + 16-lane reduce + atomicAdd ----------
// wave tile 64x64 at (row0 + wm*64, n0 + wn*64); acc[m][n] 16x16 frags.
__device__ __forceinline__ void score_epilogue(
    f32x4 acc[4][4], int n0, int wm, int wn, int lane, size_t row0,
    const float* __restrict__ decp, const float* __restrict__ covp,
    const float* __restrict__ V, float* __restrict__ scores)
{
    int colb = n0 + wn * 64 + (lane & 15);
    size_t rowg = row0 + (size_t)wm * 64;
    int b = (int)(rowg >> 11); // / S_
    float cb = covp[b];
    float vv[4], dp[4];
    #pragma unroll
    for (int n = 0; n < 4; ++n) {
        int c = colb + n * 16;
        vv[n] = V[c];
        dp[n] = decp[b * H_ + c] + cb;
    }
    #pragma unroll
    for (int m = 0; m < 4; ++m) {
        float rs[4] = {0.f, 0.f, 0.f, 0.f};
        #pragma unroll
        for (int n = 0; n < 4; ++n) {
            f32x4 A = acc[m][n];
            #pragma unroll
            for (int j = 0; j < 4; ++j) {
                float x = A[j] + dp[n];
                float e = __expf(2.f * x);
                float th = 1.f - 2.f / (e + 1.f); // inf-safe tanh
                rs[j] += th * vv[n];
            }
        }
        #pragma unroll
        for (int off = 1; off < 16; off <<= 1) {
            #pragma unroll
            for (int j = 0; j < 4; ++j) rs[j] += __shfl_xor(rs[j], off);
        }
        if ((lane & 15) == 0) {
            size_t r = rowg + m * 16 + (lane >> 4) * 4;
            #pragma unroll
            for (int j = 0; j < 4; ++j) atomicAdd(&scores[r + j], rs[j]);
        }
    }
}

// ---------- main GEMM: 128x128 tile, 4 waves, BK=32, ring-3 (48KB) -> 3 blocks/CU ----
// m97-proven config + counted-vmcnt ring. The lever vs rounds 3-6: THREE
// independent blocks per CU (m114 cross-block overlap) instead of one big
// barrier-locked block. LDS chunk (1KB) = 16 rows x 32 k, lane-linear.
// Wave wid stages A chunks {2wid,2wid+1} + B chunks {2wid,2wid+1} (4 gload16).
// Ring-3 unrolled x3 so slot indices are compile-time. vmcnt: steady 4, tail 0.
__global__ __launch_bounds__(256, 3) void k_gemm_m97(
    const unsigned short* __restrict__ A, const unsigned short* __restrict__ Bm,
    const float* __restrict__ decp, const float* __restrict__ covp,
    const float* __restrict__ V, float* __restrict__ scores)
{
    __shared__ char lds[49152]; // 3 slots x (A 8KB | B 8KB)

    int bid = blockIdx.x;
    // bijective XCD-chunked swizzle (4096 % 8 == 0): 8 n-tiles sharing an
    // A-stripe are consecutive within one XCD's chunk.
    int xcd = bid & 7, local = bid >> 3;
    int T = xcd * 512 + local;
    int tile_m = T >> 3, tile_n = T & 7;
    size_t row0 = (size_t)tile_m * 128;
    int n0 = tile_n * 128;

    int t = threadIdx.x, lane = t & 63, wid = t >> 6; // 4 waves
    int wm = wid >> 1, wn = wid & 1;                  // 2 x 2 wave grid, 64x64/wave
    int lrow = lane & 15, lk = (lane >> 4) * 8;

    const unsigned short* gA0 = A + (row0 + (size_t)(wid * 32) + lrow) * H_ + lk;
    const unsigned short* gA1 = gA0 + (size_t)16 * H_;
    const unsigned short* gB0 = Bm + ((size_t)(n0 + wid * 32 + lrow)) * H_ + lk;
    const unsigned short* gB1 = gB0 + (size_t)16 * H_;

    f32x4 acc[4][4] = {};

    auto stage = [&](int h, int slot) {
        char* lb = lds + slot * 16384;
        gload16(gA0 + h * 32, lb + (2 * wid) * 1024);
        gload16(gA1 + h * 32, lb + (2 * wid + 1) * 1024);
        gload16(gB0 + h * 32, lb + 8192 + (2 * wid) * 1024);
        gload16(gB1 + h * 32, lb + 8192 + (2 * wid + 1) * 1024);
    };

    int aoff = wm * 4 * 1024 + lane * 16;
    int boff = 8192 + wn * 4 * 1024 + lane * 16;

    auto body = [&](int h, int slot, int pslot, bool pf) {
        const char* base = lds + slot * 16384;
        short8 af[4], bf[4];
        #pragma unroll
        for (int m = 0; m < 4; ++m) af[m] = *(const short8*)(base + aoff + m * 1024);
        #pragma unroll
        for (int n = 0; n < 4; ++n) bf[n] = *(const short8*)(base + boff + n * 1024);
        if (pf) stage(h + 2, pslot);
        __builtin_amdgcn_s_setprio(1);
        #pragma unroll
        for (int m = 0; m < 4; ++m)
            #pragma unroll
            for (int n = 0; n < 4; ++n)
                acc[m][n] = __builtin_amdgcn_mfma_f32_16x16x32_bf16(af[m], bf[n], acc[m][n], 0, 0, 0);
        __builtin_amdgcn_s_setprio(0);
    };

    // prologue: halves 0,1 in flight (8 loads/thread)
    stage(0, 0); stage(1, 1);

    for (int h = 0; h < 30; h += 3) {
        WAITV("4"); BAR(); body(h + 0, 0, 2, true);   // stages h+2 -> slot 2
        WAITV("4"); BAR(); body(h + 1, 1, 0, true);   // stages h+3 -> slot 0
        WAITV("4"); BAR(); body(h + 2, 2, 1, true);   // stages h+4 -> slot 1
    }
    WAITV("4"); BAR(); body(30, 0, 2, false);         // 31 still in flight (4 loads)
    WAITV("0"); BAR(); body(31, 1, 0, false);

    score_epilogue(acc, n0, wm, wn, lane, row0, decp, covp, V, scores);
}

// ---------- fallback GEMM (fp32 A reg-staged, 128^2) ----------
__global__ __launch_bounds__(256, 2) void k_gemm_stage32(
    const float* __restrict__ enc, const unsigned short* __restrict__ whT,
    const float* __restrict__ decp, const float* __restrict__ covp,
    const float* __restrict__ V, float* __restrict__ scores)
{
    __shared__ uint4 lds[2][1024];
    int bid = blockIdx.x;
    int xcd = bid & 7, idx = bid >> 3;
    int tile_m = xcd * 64 + (idx >> 3);
    int tile_n = idx & 7;
    int t = threadIdx.x, lane = t & 63, wid = t >> 6;
    int wm = wid >> 1, wn = wid & 1;
    size_t row0 = (size_t)tile_m * 128;
    int n0 = tile_n * 128;
    int c0 = t, c1 = t + 256;
    int blk0 = c0 >> 6, l0 = c0 & 63, r0 = blk0 * 16 + (l0 & 15), ks0 = l0 >> 4;
    int blk1 = c1 >> 6, l1 = c1 & 63, r1 = blk1 * 16 + (l1 & 15), ks1 = l1 >> 4;
    const float* pa0 = enc + (row0 + r0) * H_ + ks0 * 8;
    const float* pa1 = enc + (row0 + r1) * H_ + ks1 * 8;
    const unsigned short* pb0 = whT + (size_t)(n0 + r0) * H_ + ks0 * 8;
    const unsigned short* pb1 = whT + (size_t)(n0 + r1) * H_ + ks1 * 8;
    f32x4 acc[4][4] = {};
    float4 a0x, a0y, a1x, a1y;
    uint4 b0, b1;
    auto LOAD = [&](int kt) {
        const float4* q0 = (const float4*)(pa0 + kt * 32);
        a0x = q0[0]; a0y = q0[1];
        const float4* q1 = (const float4*)(pa1 + kt * 32);
        a1x = q1[0]; a1y = q1[1];
        b0 = *(const uint4*)(pb0 + kt * 32);
        b1 = *(const uint4*)(pb1 + kt * 32);
    };
    auto WRITE = [&](int buf) {
        lds[buf][c0] = make_uint4(pk2(a0x.x, a0x.y), pk2(a0x.z, a0x.w),
                                  pk2(a0y.x, a0y.y), pk2(a0y.z, a0y.w));
        lds[buf][c1] = make_uint4(pk2(a1x.x, a1x.y), pk2(a1x.z, a1x.w),
                                  pk2(a1y.x, a1y.y), pk2(a1y.z, a1y.w));
        lds[buf][512 + c0] = b0;
        lds[buf][512 + c1] = b1;
    };
    LOAD(0); WRITE(0); __syncthreads();
    int cur = 0;
    for (int kt = 0; kt < 32; ++kt) {
        if (kt < 31) LOAD(kt + 1);
        const short8* LA = (const short8*)&lds[cur][0];
        const short8* LB = (const short8*)&lds[cur][512];
        short8 af[4], bf[4];
        #pragma unroll
        for (int m = 0; m < 4; ++m) af[m] = LA[(wm * 4 + m) * 64 + lane];
        #pragma unroll
        for (int n = 0; n < 4; ++n) bf[n] = LB[(wn * 4 + n) * 64 + lane];
        #pragma unroll
        for (int m = 0; m < 4; ++m)
            #pragma unroll
            for (int n = 0; n < 4; ++n)
                acc[m][n] = __builtin_amdgcn_mfma_f32_16x16x32_bf16(af[m], bf[n], acc[m][n], 0, 0, 0);
        if (kt < 31) WRITE(cur ^ 1);
        __syncthreads();
        cur ^= 1;
    }
    score_epilogue(acc, n0, wm, wn, lane, row0, decp, covp, V, scores);
}

// ---------- softmax over S per b; writes attn and coverage_new ----------
__global__ void k_softmax(const float* __restrict__ scores, const float* __restrict__ cov,
                          float* __restrict__ out) {
    int b = blockIdx.x, t = threadIdx.x;
    float* attn = out + B_ * H_;
    float* covn = out + B_ * H_ + B_ * S_;
    float v[8];
    float mx = -1e30f;
    #pragma unroll
    for (int i = 0; i < 8; ++i) {
        v[i] = scores[b * S_ + i * 256 + t];
        mx = fmaxf(mx, v[i]);
    }
    for (int off = 32; off; off >>= 1) mx = fmaxf(mx, __shfl_xor(mx, off));
    __shared__ float wsm[4], wss[4];
    if ((t & 63) == 0) wsm[t >> 6] = mx;
    __syncthreads();
    mx = fmaxf(fmaxf(wsm[0], wsm[1]), fmaxf(wsm[2], wsm[3]));
    float sum = 0.f;
    #pragma unroll
    for (int i = 0; i < 8; ++i) { v[i] = __expf(v[i] - mx); sum += v[i]; }
    for (int off = 32; off; off >>= 1) sum += __shfl_xor(sum, off);
    if ((t & 63) == 0) wss[t >> 6] = sum;
    __syncthreads();
    sum = wss[0] + wss[1] + wss[2] + wss[3];
    float inv = 1.f / sum;
    #pragma unroll
    for (int i = 0; i < 8; ++i) {
        int s = i * 256 + t;
        float a = v[i] * inv;
        attn[b * S_ + s] = a;
        covn[b * S_ + s] = cov[b * S_ + s] + a;
    }
}

// ---------- context from bf16 enc ----------
__global__ void k_context_bf(const unsigned short* __restrict__ encBF,
                             const float* __restrict__ attn, float* __restrict__ ctx) {
    int b = blockIdx.y, chunk = blockIdx.x; // 16 chunks x 128 s
    int t = threadIdx.x;
    __shared__ float sa[128];
    int s0 = chunk * 128;
    if (t < 128) sa[t] = attn[b * S_ + s0 + t];
    __syncthreads();
    float4 acc = {0.f, 0.f, 0.f, 0.f};
    const unsigned short* e = encBF + ((size_t)(b * S_ + s0)) * H_ + t * 4;
    #pragma unroll 4
    for (int s = 0; s < 128; ++s) {
        u16x4 x = *(const u16x4*)(e + (size_t)s * H_);
        float a = sa[s];
        acc.x += a * bf2f(x[0]); acc.y += a * bf2f(x[1]);
        acc.z += a * bf2f(x[2]); acc.w += a * bf2f(x[3]);
    }
    float* c = ctx + b * H_ + t * 4;
    atomicAdd(c + 0, acc.x); atomicAdd(c + 1, acc.y);
    atomicAdd(c + 2, acc.z); atomicAdd(c + 3, acc.w);
}

// ---------- context from fp32 enc (fallback) ----------
__global__ void k_context_f32(const float* __restrict__ enc, const float* __restrict__ attn,
                              float* __restrict__ ctx) {
    int b = blockIdx.y, chunk = blockIdx.x;
    int t = threadIdx.x;
    __shared__ float sa[128];
    int s0 = chunk * 128;
    if (t < 128) sa[t] = attn[b * S_ + s0 + t];
    __syncthreads();
    float4 acc = {0.f, 0.f, 0.f, 0.f};
    const float4* e = (const float4*)(enc + ((size_t)b * S_ + s0) * H_) + t;
    #pragma unroll 4
    for (int s = 0; s < 128; ++s) {
        float4 x = e[(size_t)s * (H_ / 4)];
        float a = sa[s];
        acc.x += a * x.x; acc.y += a * x.y; acc.z += a * x.z; acc.w += a * x.w;
    }
    float* c = ctx + b * H_ + t * 4;
    atomicAdd(c + 0, acc.x); atomicAdd(c + 1, acc.y);
    atomicAdd(c + 2, acc.z); atomicAdd(c + 3, acc.w);
}

extern "C" void kernel_launch(void* const* d_in, const int* in_sizes, int n_in,
                              void* d_out, int out_size, void* d_ws, size_t ws_size,
                              hipStream_t stream) {
    (void)in_sizes; (void)n_in; (void)out_size;
    const float* ds  = (const float*)d_in[0];
    const float* enc = (const float*)d_in[1];
    const float* cov = (const float*)d_in[2];
    const float* Wh  = (const float*)d_in[3];
    const float* bh  = (const float*)d_in[4];
    const float* Ws  = (const float*)d_in[5];
    const float* bs  = (const float*)d_in[6];
    const float* V   = (const float*)d_in[7];
    // d_in[8] = bv: softmax-invariant constant -> unused
    const float* Wc  = (const float*)d_in[9];
    const float* bc  = (const float*)d_in[10];
    float* out = (float*)d_out;

    float* ws_scores = (float*)d_ws;                          // 65536 f32
    float* ws_decp   = ws_scores + B_ * S_;                   // 32768 f32
    float* ws_covp   = ws_decp + B_ * H_;                     // 64 f32
    unsigned short* ws_whT = (unsigned short*)(ws_covp + 64); // 1M bf16 (2MB)
    unsigned short* ws_encBF = ws_whT + (size_t)H_ * H_;      // 64M bf16 (128MB)
    const size_t need_full = ((char*)(ws_encBF + (size_t)B_ * S_ * H_)) - (char*)d_ws;

    hipMemsetAsync(ws_scores, 0, B_ * S_ * sizeof(float), stream);
    hipMemsetAsync(out, 0, B_ * H_ * sizeof(float), stream); // context accumulators

    k_whT<<<dim3(16, 16), dim3(64, 4), 0, stream>>>(Wh, ws_whT);
    k_decp<<<dim3(4, 32), 256, 0, stream>>>(ds, Ws, bs, bh, ws_decp);
    k_covp<<<32, 256, 0, stream>>>(cov, Wc, bc, ws_covp);

    if (ws_size >= need_full) {
        k_cvt<<<2048, 256, 0, stream>>>(enc, (uint4*)ws_encBF, (B_ * S_ * H_) / 8);
        k_gemm_m97<<<4096, 256, 0, stream>>>(ws_encBF, ws_whT, ws_decp, ws_covp, V, ws_scores);
        k_softmax<<<32, 256, 0, stream>>>(ws_scores, cov, out);
        k_context_bf<<<dim3(16, 32), 256, 0, stream>>>(ws_encBF, out + B_ * H_, out);
    } else {
        k_gemm_stage32<<<4096, 256, 0, stream>>>(enc, ws_whT, ws_decp, ws_covp, V, ws_scores);
        k_softmax<<<32, 256, 0, stream>>>(ws_scores, cov, out);
        k_context_f32<<<dim3(16, 32), 256, 0, stream>>>(enc, out + B_ * H_, out);
    }
}

// Round 8
// 366.429 us; speedup vs baseline: 1.1511x; 1.1511x over previous
//
#include <hip/hip_runtime.h>

#define B_ 32
#define S_ 2048
#define H_ 1024

typedef __attribute__((ext_vector_type(8))) short short8;
typedef __attribute__((ext_vector_type(4))) float f32x4;
typedef __attribute__((ext_vector_type(4))) unsigned short u16x4;

__device__ __forceinline__ unsigned short f2bf(float f) {
    unsigned u = __builtin_bit_cast(unsigned, f);
    u += 0x7FFFu + ((u >> 16) & 1u);
    return (unsigned short)(u >> 16);
}
__device__ __forceinline__ unsigned pk2(float x, float y) {
    return (unsigned)f2bf(x) | ((unsigned)f2bf(y) << 16);
}
__device__ __forceinline__ float bf2f(unsigned short u) {
    unsigned x = ((unsigned)u) << 16;
    return __builtin_bit_cast(float, x);
}

// ---------- enc fp32 -> FRAGMENT-LAYOUT bf16 ----------
// Chunk cA = M16*32 + h (1KB) holds rows M16*16..+15, k h*32..+31, lane-linear:
// slot l (16B) = row (l&15), k-slice (l>>4)*8..+8  == one wave A-fragment set.
__global__ __launch_bounds__(256) void k_cvtf(const float* __restrict__ in,
                                              unsigned short* __restrict__ out) {
    __shared__ unsigned short tile[16][1032]; // +8 pad: row stride 2064B
    int m16 = blockIdx.x;                     // 4096 m-chunks
    int t = threadIdx.x;
    const float* src = in + (size_t)m16 * 16 * H_;
    #pragma unroll
    for (int it = 0; it < 16; ++it) {
        int idx = it * 256 + t;               // float4 index in [0,4096)
        int row = idx >> 8, c4 = idx & 255;
        float4 v = ((const float4*)src)[(size_t)row * 256 + c4];
        int k = c4 * 4;
        tile[row][k + 0] = f2bf(v.x); tile[row][k + 1] = f2bf(v.y);
        tile[row][k + 2] = f2bf(v.z); tile[row][k + 3] = f2bf(v.w);
    }
    __syncthreads();
    uint4* dst = (uint4*)(out + (size_t)m16 * 32 * 512);
    #pragma unroll
    for (int it = 0; it < 8; ++it) {
        int g = it * 256 + t;                 // [0,2048): (h = g>>6, l = g&63)
        int h = g >> 6, l = g & 63;
        int row = l & 15, k0 = h * 32 + (l >> 4) * 8;
        const unsigned* t32 = (const unsigned*)&tile[row][k0];
        dst[g] = make_uint4(t32[0], t32[1], t32[2], t32[3]);
    }
}

// ---------- Wh (K,N) fp32 -> B fragment layout bf16 (2MB) ----------
// Chunk cB = N16*32 + h: slot l = col N16*16+(l&15), k h*32+(l>>4)*8..+8.
__global__ __launch_bounds__(256) void k_whTf(const float* __restrict__ Wh,
                                              unsigned short* __restrict__ out) {
    int c = blockIdx.x;                        // 64 n-chunks
    int t = threadIdx.x;
    #pragma unroll
    for (int it = 0; it < 8; ++it) {
        int g = it * 256 + t;                  // (h, l)
        int h = g >> 6, l = g & 63;
        int n = c * 16 + (l & 15);
        int k = h * 32 + (l >> 4) * 8;
        unsigned short v[8];
        #pragma unroll
        for (int j = 0; j < 8; ++j) v[j] = f2bf(Wh[(size_t)(k + j) * H_ + n]);
        uint4 q = make_uint4(((unsigned)v[0]) | ((unsigned)v[1] << 16),
                             ((unsigned)v[2]) | ((unsigned)v[3] << 16),
                             ((unsigned)v[4]) | ((unsigned)v[5] << 16),
                             ((unsigned)v[6]) | ((unsigned)v[7] << 16));
        ((uint4*)(out + ((size_t)c * 32) * 512))[g] = q;
    }
}

// ---------- prep: Wh (K,N) fp32 -> WhT (N,K) bf16 (fallback path only) ----------
__global__ void k_whT(const float* __restrict__ Wh, unsigned short* __restrict__ whT) {
    __shared__ float tile[64][65];
    int k0 = blockIdx.x * 64, n0 = blockIdx.y * 64;
    int tx = threadIdx.x, ty = threadIdx.y; // (64,4)
    #pragma unroll
    for (int i = 0; i < 16; ++i) {
        int r = ty + i * 4;
        tile[r][tx] = Wh[(size_t)(k0 + r) * H_ + n0 + tx];
    }
    __syncthreads();
    #pragma unroll
    for (int i = 0; i < 16; ++i) {
        int r = ty + i * 4;
        whT[(size_t)(n0 + r) * H_ + k0 + tx] = f2bf(tile[tx][r]);
    }
}

// ---------- prep: decp[b][n] = ds[b]@Ws[:,n] + bs[n] + bh[n] ----------
__global__ void k_decp(const float* __restrict__ ds, const float* __restrict__ Ws,
                       const float* __restrict__ bs, const float* __restrict__ bh,
                       float* __restrict__ decp) {
    int n = blockIdx.x * 256 + threadIdx.x;
    int b = blockIdx.y;
    float a0 = 0.f, a1 = 0.f, a2 = 0.f, a3 = 0.f;
    for (int h = 0; h < H_; h += 4) {
        a0 += ds[b * H_ + h + 0] * Ws[(size_t)(h + 0) * H_ + n];
        a1 += ds[b * H_ + h + 1] * Ws[(size_t)(h + 1) * H_ + n];
        a2 += ds[b * H_ + h + 2] * Ws[(size_t)(h + 2) * H_ + n];
        a3 += ds[b * H_ + h + 3] * Ws[(size_t)(h + 3) * H_ + n];
    }
    decp[b * H_ + n] = a0 + a1 + a2 + a3 + bs[n] + bh[n];
}

// ---------- prep: covp[b] = cov[b]@Wc + bc ----------
__global__ void k_covp(const float* __restrict__ cov, const float* __restrict__ Wc,
                       const float* __restrict__ bc, float* __restrict__ covp) {
    int b = blockIdx.x, t = threadIdx.x;
    float p = 0.f;
    for (int s = t; s < S_; s += 256) p += cov[b * S_ + s] * Wc[s];
    for (int off = 32; off; off >>= 1) p += __shfl_down(p, off);
    __shared__ float w[4];
    if ((t & 63) == 0) w[t >> 6] = p;
    __syncthreads();
    if (t == 0) covp[b] = w[0] + w[1] + w[2] + w[3] + bc[0];
}

// ---------- shared epilogue: tanh + V-dot + 16-lane reduce + atomicAdd ----------
__device__ __forceinline__ void score_epilogue(
    f32x4 acc[4][4], int n0, int wm, int wn, int lane, size_t row0,
    const float* __restrict__ decp, const float* __restrict__ covp,
    const float* __restrict__ V, float* __restrict__ scores)
{
    int colb = n0 + wn * 64 + (lane & 15);
    size_t rowg = row0 + (size_t)wm * 64;
    int b = (int)(rowg >> 11); // / S_
    float cb = covp[b];
    float vv[4], dp[4];
    #pragma unroll
    for (int n = 0; n < 4; ++n) {
        int c = colb + n * 16;
        vv[n] = V[c];
        dp[n] = decp[b * H_ + c] + cb;
    }
    #pragma unroll
    for (int m = 0; m < 4; ++m) {
        float rs[4] = {0.f, 0.f, 0.f, 0.f};
        #pragma unroll
        for (int n = 0; n < 4; ++n) {
            f32x4 A = acc[m][n];
            #pragma unroll
            for (int j = 0; j < 4; ++j) {
                float x = A[j] + dp[n];
                float e = __expf(2.f * x);
                float th = 1.f - 2.f / (e + 1.f); // inf-safe tanh
                rs[j] += th * vv[n];
            }
        }
        #pragma unroll
        for (int off = 1; off < 16; off <<= 1) {
            #pragma unroll
            for (int j = 0; j < 4; ++j) rs[j] += __shfl_xor(rs[j], off);
        }
        if ((lane & 15) == 0) {
            size_t r = rowg + m * 16 + (lane >> 4) * 4;
            #pragma unroll
            for (int j = 0; j < 4; ++j) atomicAdd(&scores[r + j], rs[j]);
        }
    }
}

// ---------- main GEMM: NO LDS, NO BARRIERS — direct fragment dataflow ----------
// Both operands pre-laid-out in fragment chunks (1KB = one wave frag set).
// Per K-half: 8 coalesced global_load_dwordx4 (lane-linear) + 16 MFMA.
// Double-buffered register sets; compiler inserts counted vmcnt waits per set.
// 4 waves/block (2x2 of 64x64), 128^2 block tile; waves fully independent.
__global__ __launch_bounds__(256, 3) void k_gemm_direct(
    const unsigned short* __restrict__ Af, const unsigned short* __restrict__ Bf,
    const float* __restrict__ decp, const float* __restrict__ covp,
    const float* __restrict__ V, float* __restrict__ scores)
{
    int bid = blockIdx.x;
    // bijective XCD-chunked swizzle (4096 % 8 == 0): 8 n-tiles sharing an
    // A-stripe are consecutive within one XCD's chunk.
    int xcd = bid & 7, local = bid >> 3;
    int T = xcd * 512 + local;
    int tile_m = T >> 3, tile_n = T & 7;
    size_t row0 = (size_t)tile_m * 128;
    int n0 = tile_n * 128;

    int t = threadIdx.x, lane = t & 63, wid = t >> 6; // 4 waves
    int wm = wid >> 1, wn = wid & 1;                  // 2x2, 64x64 per wave

    // fragment base pointers: chunk (M16,h) at (M16*32+h)*1KB; m-step = 32KB
    const unsigned short* pA = Af + ((size_t)(tile_m * 8 + wm * 4) * 32) * 512 + lane * 8;
    const unsigned short* pB = Bf + ((size_t)(tile_n * 8 + wn * 4) * 32) * 512 + lane * 8;

    f32x4 acc[4][4] = {};
    short8 a0[4], b0[4], a1[4], b1[4];

#define LDSET(AF, BF, h) do { \
    _Pragma("unroll") \
    for (int m_ = 0; m_ < 4; ++m_) AF[m_] = *(const short8*)(pA + (size_t)m_ * 16384 + (h) * 512); \
    _Pragma("unroll") \
    for (int n_ = 0; n_ < 4; ++n_) BF[n_] = *(const short8*)(pB + (size_t)n_ * 16384 + (h) * 512); \
} while (0)
#define MFMA16(AF, BF) do { \
    __builtin_amdgcn_s_setprio(1); \
    _Pragma("unroll") \
    for (int m_ = 0; m_ < 4; ++m_) \
        _Pragma("unroll") \
        for (int n_ = 0; n_ < 4; ++n_) \
            acc[m_][n_] = __builtin_amdgcn_mfma_f32_16x16x32_bf16(AF[m_], BF[n_], acc[m_][n_], 0, 0, 0); \
    __builtin_amdgcn_s_setprio(0); \
} while (0)

    LDSET(a0, b0, 0);
    #pragma unroll
    for (int h = 0; h < 32; h += 2) {
        LDSET(a1, b1, h + 1);      // prefetch next half into alternate set
        MFMA16(a0, b0);
        if (h + 2 < 32) LDSET(a0, b0, h + 2);
        MFMA16(a1, b1);
    }
#undef LDSET
#undef MFMA16

    score_epilogue(acc, n0, wm, wn, lane, row0, decp, covp, V, scores);
}

// ---------- fallback GEMM (fp32 A reg-staged, 128^2) ----------
__global__ __launch_bounds__(256, 2) void k_gemm_stage32(
    const float* __restrict__ enc, const unsigned short* __restrict__ whT,
    const float* __restrict__ decp, const float* __restrict__ covp,
    const float* __restrict__ V, float* __restrict__ scores)
{
    __shared__ uint4 lds[2][1024];
    int bid = blockIdx.x;
    int xcd = bid & 7, idx = bid >> 3;
    int tile_m = xcd * 64 + (idx >> 3);
    int tile_n = idx & 7;
    int t = threadIdx.x, lane = t & 63, wid = t >> 6;
    int wm = wid >> 1, wn = wid & 1;
    size_t row0 = (size_t)tile_m * 128;
    int n0 = tile_n * 128;
    int c0 = t, c1 = t + 256;
    int blk0 = c0 >> 6, l0 = c0 & 63, r0 = blk0 * 16 + (l0 & 15), ks0 = l0 >> 4;
    int blk1 = c1 >> 6, l1 = c1 & 63, r1 = blk1 * 16 + (l1 & 15), ks1 = l1 >> 4;
    const float* pa0 = enc + (row0 + r0) * H_ + ks0 * 8;
    const float* pa1 = enc + (row0 + r1) * H_ + ks1 * 8;
    const unsigned short* pb0 = whT + (size_t)(n0 + r0) * H_ + ks0 * 8;
    const unsigned short* pb1 = whT + (size_t)(n0 + r1) * H_ + ks1 * 8;
    f32x4 acc[4][4] = {};
    float4 a0x, a0y, a1x, a1y;
    uint4 b0, b1;
    auto LOAD = [&](int kt) {
        const float4* q0 = (const float4*)(pa0 + kt * 32);
        a0x = q0[0]; a0y = q0[1];
        const float4* q1 = (const float4*)(pa1 + kt * 32);
        a1x = q1[0]; a1y = q1[1];
        b0 = *(const uint4*)(pb0 + kt * 32);
        b1 = *(const uint4*)(pb1 + kt * 32);
    };
    auto WRITE = [&](int buf) {
        lds[buf][c0] = make_uint4(pk2(a0x.x, a0x.y), pk2(a0x.z, a0x.w),
                                  pk2(a0y.x, a0y.y), pk2(a0y.z, a0y.w));
        lds[buf][c1] = make_uint4(pk2(a1x.x, a1x.y), pk2(a1x.z, a1x.w),
                                  pk2(a1y.x, a1y.y), pk2(a1y.z, a1y.w));
        lds[buf][512 + c0] = b0;
        lds[buf][512 + c1] = b1;
    };
    LOAD(0); WRITE(0); __syncthreads();
    int cur = 0;
    for (int kt = 0; kt < 32; ++kt) {
        if (kt < 31) LOAD(kt + 1);
        const short8* LA = (const short8*)&lds[cur][0];
        const short8* LB = (const short8*)&lds[cur][512];
        short8 af[4], bf[4];
        #pragma unroll
        for (int m = 0; m < 4; ++m) af[m] = LA[(wm * 4 + m) * 64 + lane];
        #pragma unroll
        for (int n = 0; n < 4; ++n) bf[n] = LB[(wn * 4 + n) * 64 + lane];
        #pragma unroll
        for (int m = 0; m < 4; ++m)
            #pragma unroll
            for (int n = 0; n < 4; ++n)
                acc[m][n] = __builtin_amdgcn_mfma_f32_16x16x32_bf16(af[m], bf[n], acc[m][n], 0, 0, 0);
        if (kt < 31) WRITE(cur ^ 1);
        __syncthreads();
        cur ^= 1;
    }
    score_epilogue(acc, n0, wm, wn, lane, row0, decp, covp, V, scores);
}

// ---------- softmax over S per b; writes attn and coverage_new ----------
__global__ void k_softmax(const float* __restrict__ scores, const float* __restrict__ cov,
                          float* __restrict__ out) {
    int b = blockIdx.x, t = threadIdx.x;
    float* attn = out + B_ * H_;
    float* covn = out + B_ * H_ + B_ * S_;
    float v[8];
    float mx = -1e30f;
    #pragma unroll
    for (int i = 0; i < 8; ++i) {
        v[i] = scores[b * S_ + i * 256 + t];
        mx = fmaxf(mx, v[i]);
    }
    for (int off = 32; off; off >>= 1) mx = fmaxf(mx, __shfl_xor(mx, off));
    __shared__ float wsm[4], wss[4];
    if ((t & 63) == 0) wsm[t >> 6] = mx;
    __syncthreads();
    mx = fmaxf(fmaxf(wsm[0], wsm[1]), fmaxf(wsm[2], wsm[3]));
    float sum = 0.f;
    #pragma unroll
    for (int i = 0; i < 8; ++i) { v[i] = __expf(v[i] - mx); sum += v[i]; }
    for (int off = 32; off; off >>= 1) sum += __shfl_xor(sum, off);
    if ((t & 63) == 0) wss[t >> 6] = sum;
    __syncthreads();
    sum = wss[0] + wss[1] + wss[2] + wss[3];
    float inv = 1.f / sum;
    #pragma unroll
    for (int i = 0; i < 8; ++i) {
        int s = i * 256 + t;
        float a = v[i] * inv;
        attn[b * S_ + s] = a;
        covn[b * S_ + s] = cov[b * S_ + s] + a;
    }
}

// ---------- context from fp32 enc ----------
__global__ void k_context_f32(const float* __restrict__ enc, const float* __restrict__ attn,
                              float* __restrict__ ctx) {
    int b = blockIdx.y, chunk = blockIdx.x;
    int t = threadIdx.x;
    __shared__ float sa[128];
    int s0 = chunk * 128;
    if (t < 128) sa[t] = attn[b * S_ + s0 + t];
    __syncthreads();
    float4 acc = {0.f, 0.f, 0.f, 0.f};
    const float4* e = (const float4*)(enc + ((size_t)b * S_ + s0) * H_) + t;
    #pragma unroll 4
    for (int s = 0; s < 128; ++s) {
        float4 x = e[(size_t)s * (H_ / 4)];
        float a = sa[s];
        acc.x += a * x.x; acc.y += a * x.y; acc.z += a * x.z; acc.w += a * x.w;
    }
    float* c = ctx + b * H_ + t * 4;
    atomicAdd(c + 0, acc.x); atomicAdd(c + 1, acc.y);
    atomicAdd(c + 2, acc.z); atomicAdd(c + 3, acc.w);
}

extern "C" void kernel_launch(void* const* d_in, const int* in_sizes, int n_in,
                              void* d_out, int out_size, void* d_ws, size_t ws_size,
                              hipStream_t stream) {
    (void)in_sizes; (void)n_in; (void)out_size;
    const float* ds  = (const float*)d_in[0];
    const float* enc = (const float*)d_in[1];
    const float* cov = (const float*)d_in[2];
    const float* Wh  = (const float*)d_in[3];
    const float* bh  = (const float*)d_in[4];
    const float* Ws  = (const float*)d_in[5];
    const float* bs  = (const float*)d_in[6];
    const float* V   = (const float*)d_in[7];
    // d_in[8] = bv: softmax-invariant constant -> unused
    const float* Wc  = (const float*)d_in[9];
    const float* bc  = (const float*)d_in[10];
    float* out = (float*)d_out;

    float* ws_scores = (float*)d_ws;                          // 65536 f32
    float* ws_decp   = ws_scores + B_ * S_;                   // 32768 f32
    float* ws_covp   = ws_decp + B_ * H_;                     // 64 f32
    unsigned short* ws_whTf = (unsigned short*)(ws_covp + 64); // 1M bf16 (2MB)
    unsigned short* ws_encf = ws_whTf + (size_t)H_ * H_;      // 64M bf16 (128MB)
    const size_t need_full = ((char*)(ws_encf + (size_t)B_ * S_ * H_)) - (char*)d_ws;

    hipMemsetAsync(ws_scores, 0, B_ * S_ * sizeof(float), stream);
    hipMemsetAsync(out, 0, B_ * H_ * sizeof(float), stream); // context accumulators

    k_decp<<<dim3(4, 32), 256, 0, stream>>>(ds, Ws, bs, bh, ws_decp);
    k_covp<<<32, 256, 0, stream>>>(cov, Wc, bc, ws_covp);

    if (ws_size >= need_full) {
        k_whTf<<<64, 256, 0, stream>>>(Wh, ws_whTf);
        k_cvtf<<<4096, 256, 0, stream>>>(enc, ws_encf);
        k_gemm_direct<<<4096, 256, 0, stream>>>(ws_encf, ws_whTf, ws_decp, ws_covp, V, ws_scores);
        k_softmax<<<32, 256, 0, stream>>>(ws_scores, cov, out);
        k_context_f32<<<dim3(16, 32), 256, 0, stream>>>(enc, out + B_ * H_, out);
    } else {
        k_whT<<<dim3(16, 16), dim3(64, 4), 0, stream>>>(Wh, ws_whTf);
        k_gemm_stage32<<<4096, 256, 0, stream>>>(enc, ws_whTf, ws_decp, ws_covp, V, ws_scores);
        k_softmax<<<32, 256, 0, stream>>>(ws_scores, cov, out);
        k_context_f32<<<dim3(16, 32), 256, 0, stream>>>(enc, out + B_ * H_, out);
    }
}

// Round 9
// 347.456 us; speedup vs baseline: 1.2140x; 1.0546x over previous
//
#include <hip/hip_runtime.h>

#define B_ 32
#define S_ 2048
#define H_ 1024

typedef __attribute__((ext_vector_type(8))) short short8;
typedef __attribute__((ext_vector_type(4))) float f32x4;
typedef __attribute__((ext_vector_type(4))) unsigned short u16x4;

__device__ __forceinline__ unsigned short f2bf(float f) {
    unsigned u = __builtin_bit_cast(unsigned, f);
    u += 0x7FFFu + ((u >> 16) & 1u);
    return (unsigned short)(u >> 16);
}
__device__ __forceinline__ unsigned pk2(float x, float y) {
    return (unsigned)f2bf(x) | ((unsigned)f2bf(y) << 16);
}
__device__ __forceinline__ float bf2f(unsigned short u) {
    unsigned x = ((unsigned)u) << 16;
    return __builtin_bit_cast(float, x);
}
__device__ __forceinline__ void gload16(const void* g, void* l) {
    __builtin_amdgcn_global_load_lds((const __attribute__((address_space(1))) void*)g,
                                     (__attribute__((address_space(3))) void*)l, 16, 0, 0);
}

#define WAITV(nstr) asm volatile("s_waitcnt vmcnt(" nstr ")" ::: "memory")
#define BAR() __builtin_amdgcn_s_barrier()

// ---------- enc fp32 -> bf16 (row-major) ----------
__global__ void k_cvt(const float* __restrict__ in, uint4* __restrict__ out, int ngroups) {
    int i = blockIdx.x * blockDim.x + threadIdx.x;
    int stride = gridDim.x * blockDim.x;
    for (; i < ngroups; i += stride) {
        const float4* p = (const float4*)in + (size_t)i * 2;
        float4 x = p[0], y = p[1];
        out[i] = make_uint4(pk2(x.x, x.y), pk2(x.z, x.w), pk2(y.x, y.y), pk2(y.z, y.w));
    }
}

// ---------- prep: Wh (K,N) fp32 -> WhT (N,K) bf16 ----------
__global__ void k_whT(const float* __restrict__ Wh, unsigned short* __restrict__ whT) {
    __shared__ float tile[64][65];
    int k0 = blockIdx.x * 64, n0 = blockIdx.y * 64;
    int tx = threadIdx.x, ty = threadIdx.y; // (64,4)
    #pragma unroll
    for (int i = 0; i < 16; ++i) {
        int r = ty + i * 4;
        tile[r][tx] = Wh[(size_t)(k0 + r) * H_ + n0 + tx];
    }
    __syncthreads();
    #pragma unroll
    for (int i = 0; i < 16; ++i) {
        int r = ty + i * 4;
        whT[(size_t)(n0 + r) * H_ + k0 + tx] = f2bf(tile[tx][r]);
    }
}

// ---------- prep: decp[b][n] = ds[b]@Ws[:,n] + bs[n] + bh[n] ----------
__global__ void k_decp(const float* __restrict__ ds, const float* __restrict__ Ws,
                       const float* __restrict__ bs, const float* __restrict__ bh,
                       float* __restrict__ decp) {
    int n = blockIdx.x * 256 + threadIdx.x;
    int b = blockIdx.y;
    float a0 = 0.f, a1 = 0.f, a2 = 0.f, a3 = 0.f;
    for (int h = 0; h < H_; h += 4) {
        a0 += ds[b * H_ + h + 0] * Ws[(size_t)(h + 0) * H_ + n];
        a1 += ds[b * H_ + h + 1] * Ws[(size_t)(h + 1) * H_ + n];
        a2 += ds[b * H_ + h + 2] * Ws[(size_t)(h + 2) * H_ + n];
        a3 += ds[b * H_ + h + 3] * Ws[(size_t)(h + 3) * H_ + n];
    }
    decp[b * H_ + n] = a0 + a1 + a2 + a3 + bs[n] + bh[n];
}

// ---------- prep: covp[b] = cov[b]@Wc + bc ----------
__global__ void k_covp(const float* __restrict__ cov, const float* __restrict__ Wc,
                       const float* __restrict__ bc, float* __restrict__ covp) {
    int b = blockIdx.x, t = threadIdx.x;
    float p = 0.f;
    for (int s = t; s < S_; s += 256) p += cov[b * S_ + s] * Wc[s];
    for (int off = 32; off; off >>= 1) p += __shfl_down(p, off);
    __shared__ float w[4];
    if ((t & 63) == 0) w[t >> 6] = p;
    __syncthreads();
    if (t == 0) covp[b] = w[0] + w[1] + w[2] + w[3] + bc[0];
}

// ---------- main GEMM: 256^2 block, 4 waves x 128x128 wave tile, ring-3 ----------
// Arithmetic-intensity fix: per K=32 half per wave: 16 ds_read_b128 + 64 MFMA
// (ratio 4:1 vs previous 2.2:1) -> LDS port 768 cyc/half/CU << MFMA 1242.
// acc = 256 VGPR, ~330 total, 1 wave/SIMD (single wave saturates matrix pipe).
// LDS chunk (1KB) = 16 rows x 32 k lane-linear; ring-3 x 32KB; vmcnt(8) steady.
__global__ __launch_bounds__(256, 1) void k_gemm_fat(
    const unsigned short* __restrict__ A, const unsigned short* __restrict__ Bm,
    const float* __restrict__ decp, const float* __restrict__ covp,
    const float* __restrict__ V, float* __restrict__ scores)
{
    __shared__ char lds[98304]; // 3 slots x (A 16KB | B 16KB)

    int bid = blockIdx.x;
    // bijective XCD-chunked swizzle (1024 % 8 == 0): 4 n-tiles sharing an
    // A-stripe are consecutive within one XCD's chunk.
    int xcd = bid & 7, local = bid >> 3;
    int T = xcd * 128 + local;
    int tile_m = T >> 2, tile_n = T & 3;
    size_t row0 = (size_t)tile_m * 256;
    int n0 = tile_n * 256;

    int t = threadIdx.x, lane = t & 63, wid = t >> 6; // 4 waves
    int wm = wid >> 1, wn = wid & 1;                  // 2x2 grid of 128x128
    int lrow = lane & 15, lk = (lane >> 4) * 8;

    // staging: wave wid owns A chunks {4wid..4wid+3} and B chunks {4wid..4wid+3}
    const unsigned short* gA[4];
    const unsigned short* gB[4];
    #pragma unroll
    for (int c = 0; c < 4; ++c) {
        gA[c] = A + (row0 + (size_t)((4 * wid + c) * 16) + lrow) * H_ + lk;
        gB[c] = Bm + ((size_t)(n0 + (4 * wid + c) * 16 + lrow)) * H_ + lk;
    }

    f32x4 acc[8][8] = {};

    auto stage = [&](int h, int slot) {
        char* lb = lds + slot * 32768;
        #pragma unroll
        for (int c = 0; c < 4; ++c) {
            gload16(gA[c] + h * 32, lb + (4 * wid + c) * 1024);
            gload16(gB[c] + h * 32, lb + 16384 + (4 * wid + c) * 1024);
        }
    };

    int aoff = wm * 8 * 1024 + lane * 16;
    int boff = 16384 + wn * 8 * 1024 + lane * 16;

    auto body = [&](int h, int slot, int pslot, bool pf) {
        const char* base = lds + slot * 32768;
        short8 af[8], bf[8];
        #pragma unroll
        for (int m = 0; m < 8; ++m) af[m] = *(const short8*)(base + aoff + m * 1024);
        #pragma unroll
        for (int n = 0; n < 8; ++n) bf[n] = *(const short8*)(base + boff + n * 1024);
        if (pf) stage(h + 2, pslot);
        __builtin_amdgcn_s_setprio(1);
        #pragma unroll
        for (int m = 0; m < 8; ++m)
            #pragma unroll
            for (int n = 0; n < 8; ++n)
                acc[m][n] = __builtin_amdgcn_mfma_f32_16x16x32_bf16(af[m], bf[n], acc[m][n], 0, 0, 0);
        __builtin_amdgcn_s_setprio(0);
    };

    // prologue: halves 0,1 in flight (16 loads/thread)
    stage(0, 0); stage(1, 1);

    for (int h = 0; h < 30; h += 3) {
        WAITV("8"); BAR(); body(h + 0, 0, 2, true);   // stages h+2 -> slot 2
        WAITV("8"); BAR(); body(h + 1, 1, 0, true);   // stages h+3 -> slot 0
        WAITV("8"); BAR(); body(h + 2, 2, 1, true);   // stages h+4 -> slot 1
    }
    WAITV("8"); BAR(); body(30, 0, 2, false);         // 31 in flight (8 loads)
    WAITV("0"); BAR(); body(31, 1, 0, false);

    // ---- epilogue: tanh + V-dot + 16-lane reduce + atomicAdd ----
    int colb = n0 + wn * 128 + (lane & 15);
    size_t rowg = row0 + (size_t)wm * 128;
    int b = (int)(row0 >> 11); // block within one batch (2048 % 256 == 0)
    float cb = covp[b];
    float vv[8], dp[8];
    #pragma unroll
    for (int n = 0; n < 8; ++n) {
        int c = colb + n * 16;
        vv[n] = V[c];
        dp[n] = decp[b * H_ + c] + cb;
    }
    #pragma unroll
    for (int m = 0; m < 8; ++m) {
        float rs[4] = {0.f, 0.f, 0.f, 0.f};
        #pragma unroll
        for (int n = 0; n < 8; ++n) {
            f32x4 Aq = acc[m][n];
            #pragma unroll
            for (int j = 0; j < 4; ++j) {
                float x = Aq[j] + dp[n];
                float e = __expf(2.f * x);
                float th = 1.f - 2.f / (e + 1.f); // inf-safe tanh
                rs[j] += th * vv[n];
            }
        }
        #pragma unroll
        for (int off = 1; off < 16; off <<= 1) {
            #pragma unroll
            for (int j = 0; j < 4; ++j) rs[j] += __shfl_xor(rs[j], off);
        }
        if ((lane & 15) == 0) {
            size_t r = rowg + m * 16 + (lane >> 4) * 4;
            #pragma unroll
            for (int j = 0; j < 4; ++j) atomicAdd(&scores[r + j], rs[j]);
        }
    }
}

// ---------- fallback epilogue (4-wave 64x64 kernel) ----------
__device__ __forceinline__ void score_epilogue(
    f32x4 acc[4][4], int n0, int wm, int wn, int lane, size_t row0,
    const float* __restrict__ decp, const float* __restrict__ covp,
    const float* __restrict__ V, float* __restrict__ scores)
{
    int colb = n0 + wn * 64 + (lane & 15);
    size_t rowg = row0 + (size_t)wm * 64;
    int b = (int)(rowg >> 11);
    float cb = covp[b];
    float vv[4], dp[4];
    #pragma unroll
    for (int n = 0; n < 4; ++n) {
        int c = colb + n * 16;
        vv[n] = V[c];
        dp[n] = decp[b * H_ + c] + cb;
    }
    #pragma unroll
    for (int m = 0; m < 4; ++m) {
        float rs[4] = {0.f, 0.f, 0.f, 0.f};
        #pragma unroll
        for (int n = 0; n < 4; ++n) {
            f32x4 A = acc[m][n];
            #pragma unroll
            for (int j = 0; j < 4; ++j) {
                float x = A[j] + dp[n];
                float e = __expf(2.f * x);
                float th = 1.f - 2.f / (e + 1.f);
                rs[j] += th * vv[n];
            }
        }
        #pragma unroll
        for (int off = 1; off < 16; off <<= 1) {
            #pragma unroll
            for (int j = 0; j < 4; ++j) rs[j] += __shfl_xor(rs[j], off);
        }
        if ((lane & 15) == 0) {
            size_t r = rowg + m * 16 + (lane >> 4) * 4;
            #pragma unroll
            for (int j = 0; j < 4; ++j) atomicAdd(&scores[r + j], rs[j]);
        }
    }
}

// ---------- fallback GEMM (fp32 A reg-staged, 128^2) ----------
__global__ __launch_bounds__(256, 2) void k_gemm_stage32(
    const float* __restrict__ enc, const unsigned short* __restrict__ whT,
    const float* __restrict__ decp, const float* __restrict__ covp,
    const float* __restrict__ V, float* __restrict__ scores)
{
    __shared__ uint4 lds[2][1024];
    int bid = blockIdx.x;
    int xcd = bid & 7, idx = bid >> 3;
    int tile_m = xcd * 64 + (idx >> 3);
    int tile_n = idx & 7;
    int t = threadIdx.x, lane = t & 63, wid = t >> 6;
    int wm = wid >> 1, wn = wid & 1;
    size_t row0 = (size_t)tile_m * 128;
    int n0 = tile_n * 128;
    int c0 = t, c1 = t + 256;
    int blk0 = c0 >> 6, l0 = c0 & 63, r0 = blk0 * 16 + (l0 & 15), ks0 = l0 >> 4;
    int blk1 = c1 >> 6, l1 = c1 & 63, r1 = blk1 * 16 + (l1 & 15), ks1 = l1 >> 4;
    const float* pa0 = enc + (row0 + r0) * H_ + ks0 * 8;
    const float* pa1 = enc + (row0 + r1) * H_ + ks1 * 8;
    const unsigned short* pb0 = whT + (size_t)(n0 + r0) * H_ + ks0 * 8;
    const unsigned short* pb1 = whT + (size_t)(n0 + r1) * H_ + ks1 * 8;
    f32x4 acc[4][4] = {};
    float4 a0x, a0y, a1x, a1y;
    uint4 b0, b1;
    auto LOAD = [&](int kt) {
        const float4* q0 = (const float4*)(pa0 + kt * 32);
        a0x = q0[0]; a0y = q0[1];
        const float4* q1 = (const float4*)(pa1 + kt * 32);
        a1x = q1[0]; a1y = q1[1];
        b0 = *(const uint4*)(pb0 + kt * 32);
        b1 = *(const uint4*)(pb1 + kt * 32);
    };
    auto WRITE = [&](int buf) {
        lds[buf][c0] = make_uint4(pk2(a0x.x, a0x.y), pk2(a0x.z, a0x.w),
                                  pk2(a0y.x, a0y.y), pk2(a0y.z, a0y.w));
        lds[buf][c1] = make_uint4(pk2(a1x.x, a1x.y), pk2(a1x.z, a1x.w),
                                  pk2(a1y.x, a1y.y), pk2(a1y.z, a1y.w));
        lds[buf][512 + c0] = b0;
        lds[buf][512 + c1] = b1;
    };
    LOAD(0); WRITE(0); __syncthreads();
    int cur = 0;
    for (int kt = 0; kt < 32; ++kt) {
        if (kt < 31) LOAD(kt + 1);
        const short8* LA = (const short8*)&lds[cur][0];
        const short8* LB = (const short8*)&lds[cur][512];
        short8 af[4], bf[4];
        #pragma unroll
        for (int m = 0; m < 4; ++m) af[m] = LA[(wm * 4 + m) * 64 + lane];
        #pragma unroll
        for (int n = 0; n < 4; ++n) bf[n] = LB[(wn * 4 + n) * 64 + lane];
        #pragma unroll
        for (int m = 0; m < 4; ++m)
            #pragma unroll
            for (int n = 0; n < 4; ++n)
                acc[m][n] = __builtin_amdgcn_mfma_f32_16x16x32_bf16(af[m], bf[n], acc[m][n], 0, 0, 0);
        if (kt < 31) WRITE(cur ^ 1);
        __syncthreads();
        cur ^= 1;
    }
    score_epilogue(acc, n0, wm, wn, lane, row0, decp, covp, V, scores);
}

// ---------- softmax over S per b; writes attn and coverage_new ----------
__global__ void k_softmax(const float* __restrict__ scores, const float* __restrict__ cov,
                          float* __restrict__ out) {
    int b = blockIdx.x, t = threadIdx.x;
    float* attn = out + B_ * H_;
    float* covn = out + B_ * H_ + B_ * S_;
    float v[8];
    float mx = -1e30f;
    #pragma unroll
    for (int i = 0; i < 8; ++i) {
        v[i] = scores[b * S_ + i * 256 + t];
        mx = fmaxf(mx, v[i]);
    }
    for (int off = 32; off; off >>= 1) mx = fmaxf(mx, __shfl_xor(mx, off));
    __shared__ float wsm[4], wss[4];
    if ((t & 63) == 0) wsm[t >> 6] = mx;
    __syncthreads();
    mx = fmaxf(fmaxf(wsm[0], wsm[1]), fmaxf(wsm[2], wsm[3]));
    float sum = 0.f;
    #pragma unroll
    for (int i = 0; i < 8; ++i) { v[i] = __expf(v[i] - mx); sum += v[i]; }
    for (int off = 32; off; off >>= 1) sum += __shfl_xor(sum, off);
    if ((t & 63) == 0) wss[t >> 6] = sum;
    __syncthreads();
    sum = wss[0] + wss[1] + wss[2] + wss[3];
    float inv = 1.f / sum;
    #pragma unroll
    for (int i = 0; i < 8; ++i) {
        int s = i * 256 + t;
        float a = v[i] * inv;
        attn[b * S_ + s] = a;
        covn[b * S_ + s] = cov[b * S_ + s] + a;
    }
}

// ---------- context from bf16 enc ----------
__global__ void k_context_bf(const unsigned short* __restrict__ encBF,
                             const float* __restrict__ attn, float* __restrict__ ctx) {
    int b = blockIdx.y, chunk = blockIdx.x; // 16 chunks x 128 s
    int t = threadIdx.x;
    __shared__ float sa[128];
    int s0 = chunk * 128;
    if (t < 128) sa[t] = attn[b * S_ + s0 + t];
    __syncthreads();
    float4 acc = {0.f, 0.f, 0.f, 0.f};
    const unsigned short* e = encBF + ((size_t)(b * S_ + s0)) * H_ + t * 4;
    #pragma unroll 4
    for (int s = 0; s < 128; ++s) {
        u16x4 x = *(const u16x4*)(e + (size_t)s * H_);
        float a = sa[s];
        acc.x += a * bf2f(x[0]); acc.y += a * bf2f(x[1]);
        acc.z += a * bf2f(x[2]); acc.w += a * bf2f(x[3]);
    }
    float* c = ctx + b * H_ + t * 4;
    atomicAdd(c + 0, acc.x); atomicAdd(c + 1, acc.y);
    atomicAdd(c + 2, acc.z); atomicAdd(c + 3, acc.w);
}

// ---------- context from fp32 enc (fallback) ----------
__global__ void k_context_f32(const float* __restrict__ enc, const float* __restrict__ attn,
                              float* __restrict__ ctx) {
    int b = blockIdx.y, chunk = blockIdx.x;
    int t = threadIdx.x;
    __shared__ float sa[128];
    int s0 = chunk * 128;
    if (t < 128) sa[t] = attn[b * S_ + s0 + t];
    __syncthreads();
    float4 acc = {0.f, 0.f, 0.f, 0.f};
    const float4* e = (const float4*)(enc + ((size_t)b * S_ + s0) * H_) + t;
    #pragma unroll 4
    for (int s = 0; s < 128; ++s) {
        float4 x = e[(size_t)s * (H_ / 4)];
        float a = sa[s];
        acc.x += a * x.x; acc.y += a * x.y; acc.z += a * x.z; acc.w += a * x.w;
    }
    float* c = ctx + b * H_ + t * 4;
    atomicAdd(c + 0, acc.x); atomicAdd(c + 1, acc.y);
    atomicAdd(c + 2, acc.z); atomicAdd(c + 3, acc.w);
}

extern "C" void kernel_launch(void* const* d_in, const int* in_sizes, int n_in,
                              void* d_out, int out_size, void* d_ws, size_t ws_size,
                              hipStream_t stream) {
    (void)in_sizes; (void)n_in; (void)out_size;
    const float* ds  = (const float*)d_in[0];
    const float* enc = (const float*)d_in[1];
    const float* cov = (const float*)d_in[2];
    const float* Wh  = (const float*)d_in[3];
    const float* bh  = (const float*)d_in[4];
    const float* Ws  = (const float*)d_in[5];
    const float* bs  = (const float*)d_in[6];
    const float* V   = (const float*)d_in[7];
    // d_in[8] = bv: softmax-invariant constant -> unused
    const float* Wc  = (const float*)d_in[9];
    const float* bc  = (const float*)d_in[10];
    float* out = (float*)d_out;

    float* ws_scores = (float*)d_ws;                          // 65536 f32
    float* ws_decp   = ws_scores + B_ * S_;                   // 32768 f32
    float* ws_covp   = ws_decp + B_ * H_;                     // 64 f32
    unsigned short* ws_whT = (unsigned short*)(ws_covp + 64); // 1M bf16 (2MB)
    unsigned short* ws_encBF = ws_whT + (size_t)H_ * H_;      // 64M bf16 (128MB)
    const size_t need_full = ((char*)(ws_encBF + (size_t)B_ * S_ * H_)) - (char*)d_ws;

    hipMemsetAsync(ws_scores, 0, B_ * S_ * sizeof(float), stream);
    hipMemsetAsync(out, 0, B_ * H_ * sizeof(float), stream); // context accumulators

    k_whT<<<dim3(16, 16), dim3(64, 4), 0, stream>>>(Wh, ws_whT);
    k_decp<<<dim3(4, 32), 256, 0, stream>>>(ds, Ws, bs, bh, ws_decp);
    k_covp<<<32, 256, 0, stream>>>(cov, Wc, bc, ws_covp);

    if (ws_size >= need_full) {
        k_cvt<<<2048, 256, 0, stream>>>(enc, (uint4*)ws_encBF, (B_ * S_ * H_) / 8);
        k_gemm_fat<<<1024, 256, 0, stream>>>(ws_encBF, ws_whT, ws_decp, ws_covp, V, ws_scores);
        k_softmax<<<32, 256, 0, stream>>>(ws_scores, cov, out);
        k_context_bf<<<dim3(16, 32), 256, 0, stream>>>(ws_encBF, out + B_ * H_, out);
    } else {
        k_gemm_stage32<<<4096, 256, 0, stream>>>(enc, ws_whT, ws_decp, ws_covp, V, ws_scores);
        k_softmax<<<32, 256, 0, stream>>>(ws_scores, cov, out);
        k_context_f32<<<dim3(16, 32), 256, 0, stream>>>(enc, out + B_ * H_, out);
    }
}